// Round 1
// baseline (1710.257 us; speedup 1.0000x reference)
//
#include <hip/hip_runtime.h>
#include <hip/hip_bf16.h>

#define NN 50000
#define EE 1600000
#define GG 500

// ---------------- graph preprocessing ----------------

__global__ void deg_kernel(const int* __restrict__ src, const float* __restrict__ ea,
                           float* __restrict__ deg, int e) {
  int i = blockIdx.x * blockDim.x + threadIdx.x;
  if (i < e) atomicAdd(&deg[src[i]], ea[i]);
}

__global__ void dinv_kernel(float* __restrict__ deg, int n) {
  int i = blockIdx.x * blockDim.x + threadIdx.x;
  if (i < n) { float d = deg[i]; deg[i] = (d > 0.f) ? (1.0f / sqrtf(d)) : 0.f; }
}

__global__ void hist_kernel(const int* __restrict__ dst, int* __restrict__ cnt, int e) {
  int i = blockIdx.x * blockDim.x + threadIdx.x;
  if (i < e) atomicAdd(&cnt[dst[i]], 1);
}

__global__ void scan1(const int* __restrict__ cnt, int* __restrict__ partial,
                      int* __restrict__ bsum, int n) {
  __shared__ int s[256];
  int t = threadIdx.x, i = blockIdx.x * 256 + t;
  int v = (i < n) ? cnt[i] : 0;
  s[t] = v; __syncthreads();
  for (int off = 1; off < 256; off <<= 1) {
    int xv = (t >= off) ? s[t - off] : 0;
    __syncthreads(); s[t] += xv; __syncthreads();
  }
  if (i < n) partial[i] = s[t];
  if (t == 255) bsum[blockIdx.x] = s[255];
}

__global__ void scan2(int* __restrict__ bsum, int nb) {
  __shared__ int s[256];
  int t = threadIdx.x;
  int v = (t < nb) ? bsum[t] : 0;
  s[t] = v; __syncthreads();
  for (int off = 1; off < 256; off <<= 1) {
    int xv = (t >= off) ? s[t - off] : 0;
    __syncthreads(); s[t] += xv; __syncthreads();
  }
  if (t < nb) bsum[t] = s[t];
}

__global__ void scan3(const int* __restrict__ partial, const int* __restrict__ bsum,
                      int* __restrict__ rowptr, int n) {
  int i = blockIdx.x * 256 + threadIdx.x;
  if (i < n) {
    int off = (blockIdx.x > 0) ? bsum[blockIdx.x - 1] : 0;
    rowptr[i + 1] = partial[i] + off;
    if (i == 0) rowptr[0] = 0;
  }
}

__global__ void scatter_kernel(const int* __restrict__ src, const int* __restrict__ dst,
                               const float* __restrict__ ea, const float* __restrict__ dinv,
                               const int* __restrict__ rowptr, int* __restrict__ fill,
                               int* __restrict__ csrc, float* __restrict__ cw, int e) {
  int i = blockIdx.x * blockDim.x + threadIdx.x;
  if (i < e) {
    int s = src[i], d = dst[i];
    float w = -dinv[s] * ea[i] * dinv[d];
    int pos = rowptr[d] + atomicAdd(&fill[d], 1);
    csrc[pos] = s; cw[pos] = w;
  }
}

// ---------------- sparse propagation (one wave per dst node) ----------------
// out[i] = alpha * sum_e w_e * h[src_e]  (+ subscale * sub[i])

template<int W, bool HAS_SUB>
__global__ __launch_bounds__(256) void prop_kernel(const int* __restrict__ rowptr,
    const int* __restrict__ csrc, const float* __restrict__ cw,
    const float* __restrict__ h, const float* __restrict__ sub,
    float* __restrict__ out, int n, float alpha, float subscale)
{
  int wv = blockIdx.x * 4 + (threadIdx.x >> 6);
  wv = __builtin_amdgcn_readfirstlane(wv);
  const int lane = threadIdx.x & 63;
  if (wv >= n) return;
  const int e0 = __builtin_amdgcn_readfirstlane(rowptr[wv]);
  const int e1 = __builtin_amdgcn_readfirstlane(rowptr[wv + 1]);
  if constexpr (W == 64) {
    float acc = 0.f;
    int j = e0;
    for (; j + 1 < e1; j += 2) {
      int s0 = csrc[j], s1 = csrc[j + 1];
      float w0 = cw[j], w1 = cw[j + 1];
      float v0 = h[s0 * 64 + lane], v1 = h[s1 * 64 + lane];
      acc += w0 * v0;
      acc += w1 * v1;
    }
    if (j < e1) acc += cw[j] * h[csrc[j] * 64 + lane];
    float r = alpha * acc;
    if constexpr (HAS_SUB) r += subscale * sub[(size_t)wv * 64 + lane];
    out[(size_t)wv * 64 + lane] = r;
  } else {  // W == 128, float2 per lane
    const float2* h2 = (const float2*)h;
    float2 acc; acc.x = 0.f; acc.y = 0.f;
    int j = e0;
    for (; j + 1 < e1; j += 2) {
      int s0 = csrc[j], s1 = csrc[j + 1];
      float w0 = cw[j], w1 = cw[j + 1];
      float2 va = h2[s0 * 64 + lane];
      float2 vb = h2[s1 * 64 + lane];
      acc.x += w0 * va.x; acc.y += w0 * va.y;
      acc.x += w1 * vb.x; acc.y += w1 * vb.y;
    }
    if (j < e1) {
      float wj = cw[j];
      float2 v = h2[csrc[j] * 64 + lane];
      acc.x += wj * v.x; acc.y += wj * v.y;
    }
    float2 r; r.x = alpha * acc.x; r.y = alpha * acc.y;
    if constexpr (HAS_SUB) {
      const float2* s2 = (const float2*)sub;
      float2 sv = s2[(size_t)wv * 64 + lane];
      r.x += subscale * sv.x; r.y += subscale * sv.y;
    }
    ((float2*)out)[(size_t)wv * 64 + lane] = r;
  }
}

// ---------------- dense GEMM: C[n x Co] (+)= A[n x Ci] @ Wt[Ci x Co] ----------------
// INIT: C = A@W + bias;  else C += A@W;  RELU: C = relu(C_old + A@W)

template<int Ci, int Co, bool INIT, bool RELU>
__global__ __launch_bounds__(256) void gemm_kernel(const float* __restrict__ A,
    const float* __restrict__ Wt, const float* __restrict__ bias,
    float* __restrict__ C, int n)
{
  constexpr int TN = Co / 16;   // 4 or 8
  constexpr int KC = 32;
  __shared__ float Ws[Ci * Co];
  __shared__ float As[64 * 33];
  const int tid = threadIdx.x;
  const int rb = blockIdx.x * 64;
  for (int l = tid; l < Ci * Co / 4; l += 256)
    ((float4*)Ws)[l] = ((const float4*)Wt)[l];
  const int tx = tid & 15, ty = tid >> 4;
  float acc[4][TN];
  #pragma unroll
  for (int i = 0; i < 4; i++)
    #pragma unroll
    for (int j = 0; j < TN; j++) acc[i][j] = 0.f;

  for (int ko = 0; ko < Ci; ko += KC) {
    __syncthreads();
    #pragma unroll
    for (int l2 = 0; l2 < 2; ++l2) {
      int l = tid + l2 * 256;           // 512 float4 = 64 rows x 32 cols
      int r = l >> 3, c4 = l & 7;
      int row = rb + r;
      float4 v = make_float4(0.f, 0.f, 0.f, 0.f);
      if (row < n) v = *(const float4*)&A[(size_t)row * Ci + ko + c4 * 4];
      *(float4*)&As[r * 33 + c4 * 4] = v;
    }
    __syncthreads();
    #pragma unroll
    for (int cc = 0; cc < KC; ++cc) {
      float a0 = As[(ty * 4 + 0) * 33 + cc];
      float a1 = As[(ty * 4 + 1) * 33 + cc];
      float a2 = As[(ty * 4 + 2) * 33 + cc];
      float a3 = As[(ty * 4 + 3) * 33 + cc];
      const float* wrow = &Ws[(ko + cc) * Co + tx * TN];
      float b[TN];
      *(float4*)&b[0] = *(const float4*)wrow;
      if constexpr (TN == 8) *(float4*)&b[4] = *(const float4*)(wrow + 4);
      #pragma unroll
      for (int j = 0; j < TN; j++) {
        acc[0][j] += a0 * b[j];
        acc[1][j] += a1 * b[j];
        acc[2][j] += a2 * b[j];
        acc[3][j] += a3 * b[j];
      }
    }
  }
  float bia[TN];
  if constexpr (INIT) {
    *(float4*)&bia[0] = *(const float4*)&bias[tx * TN];
    if constexpr (TN == 8) *(float4*)&bia[4] = *(const float4*)&bias[tx * TN + 4];
  }
  #pragma unroll
  for (int i = 0; i < 4; i++) {
    int row = rb + ty * 4 + i;
    if (row < n) {
      float* cp = &C[(size_t)row * Co + tx * TN];
      #pragma unroll
      for (int q = 0; q < TN; q += 4) {
        float4 v;
        v.x = acc[i][q + 0]; v.y = acc[i][q + 1]; v.z = acc[i][q + 2]; v.w = acc[i][q + 3];
        if constexpr (INIT) {
          v.x += bia[q + 0]; v.y += bia[q + 1]; v.z += bia[q + 2]; v.w += bia[q + 3];
        } else {
          float4 o = *(float4*)(cp + q);
          v.x += o.x; v.y += o.y; v.z += o.z; v.w += o.w;
        }
        if constexpr (RELU) {
          v.x = fmaxf(v.x, 0.f); v.y = fmaxf(v.y, 0.f);
          v.z = fmaxf(v.z, 0.f); v.w = fmaxf(v.w, 0.f);
        }
        *(float4*)(cp + q) = v;
      }
    }
  }
}

// ---------------- pooling + head ----------------

__global__ void pool_feat(const float* __restrict__ h, const int* __restrict__ batch,
                          float* __restrict__ pooled, int n) {
  int idx = blockIdx.x * blockDim.x + threadIdx.x;
  if (idx < n * 128) {
    int i = idx >> 7, f = idx & 127;
    atomicAdd(&pooled[batch[i] * 128 + f], h[idx]);
  }
}

__global__ void pool_cnt(const int* __restrict__ batch, float* __restrict__ gcnt, int n) {
  int i = blockIdx.x * blockDim.x + threadIdx.x;
  if (i < n) atomicAdd(&gcnt[batch[i]], 1.0f);
}

__global__ __launch_bounds__(128) void head_kernel(const float* __restrict__ pooled,
    const float* __restrict__ gcnt, const float* __restrict__ Wl,
    const float* __restrict__ bl, float* __restrict__ outp)
{
  int g = blockIdx.x, t = threadIdx.x;
  float denom = fmaxf(gcnt[g], 1.f);
  float p = pooled[g * 128 + t] / denom;
  __shared__ float s0[128], s1[128];
  s0[t] = p * Wl[t * 2 + 0];
  s1[t] = p * Wl[t * 2 + 1];
  __syncthreads();
  for (int off = 64; off > 0; off >>= 1) {
    if (t < off) { s0[t] += s0[t + off]; s1[t] += s1[t + off]; }
    __syncthreads();
  }
  if (t == 0) {
    float a = s0[0] + bl[0], b = s1[0] + bl[1];
    float m = fmaxf(a, b);
    float z = logf(expf(a - m) + expf(b - m)) + m;
    outp[g * 2 + 0] = a - z;
    outp[g * 2 + 1] = b - z;
  }
}

// ---------------- launch ----------------

extern "C" void kernel_launch(void* const* d_in, const int* in_sizes, int n_in,
                              void* d_out, int out_size, void* d_ws, size_t ws_size,
                              hipStream_t stream) {
  const float* x   = (const float*)d_in[0];
  const int*   ei  = (const int*)d_in[1];
  const float* ea  = (const float*)d_in[2];
  const int* batch = (const int*)d_in[3];
  const float* W1  = (const float*)d_in[4];
  const float* b1  = (const float*)d_in[5];
  const float* W2  = (const float*)d_in[6];
  const float* b2  = (const float*)d_in[7];
  const float* W3  = (const float*)d_in[8];
  const float* b3  = (const float*)d_in[9];
  const float* Wl  = (const float*)d_in[10];
  const float* bl  = (const float*)d_in[11];
  const int* srcv = ei;
  const int* dstv = ei + EE;

  char* w = (char*)d_ws;
  auto alloc = [&](size_t bytes) -> char* {
    char* p = w; w += (bytes + 255) & ~(size_t)255; return p;
  };
  float* deg    = (float*)alloc((size_t)NN * 4);          // becomes dinv in place
  int*   rowptr = (int*)alloc((size_t)(NN + 1) * 4);
  int*   fill   = (int*)alloc((size_t)NN * 4);
  int*   bsum   = (int*)alloc(256 * 4);
  int*   csrc   = (int*)alloc((size_t)EE * 4);
  float* cw     = (float*)alloc((size_t)EE * 4);
  float* TxA    = (float*)alloc((size_t)NN * 128 * 4);
  float* TxB    = (float*)alloc((size_t)NN * 128 * 4);
  float* h1     = (float*)alloc((size_t)NN * 64 * 4);
  float* h2     = (float*)alloc((size_t)NN * 64 * 4);
  float* h3     = (float*)alloc((size_t)NN * 128 * 4);
  float* pooled = (float*)alloc((size_t)(GG * 128 + GG) * 4);
  float* gcnt   = pooled + GG * 128;
  int* partial  = (int*)TxA;   // scan scratch (TxA unused until props)

  hipMemsetAsync(deg, 0, (size_t)NN * 4, stream);
  hipMemsetAsync(fill, 0, (size_t)NN * 4, stream);
  hipMemsetAsync(pooled, 0, (size_t)(GG * 128 + GG) * 4, stream);

  deg_kernel<<<(EE + 255) / 256, 256, 0, stream>>>(srcv, ea, deg, EE);
  dinv_kernel<<<(NN + 255) / 256, 256, 0, stream>>>(deg, NN);
  hist_kernel<<<(EE + 255) / 256, 256, 0, stream>>>(dstv, fill, EE);
  const int nb = (NN + 255) / 256;  // 196
  scan1<<<nb, 256, 0, stream>>>(fill, partial, bsum, NN);
  scan2<<<1, 256, 0, stream>>>(bsum, nb);
  scan3<<<nb, 256, 0, stream>>>(partial, bsum, rowptr, NN);
  hipMemsetAsync(fill, 0, (size_t)NN * 4, stream);
  scatter_kernel<<<(EE + 255) / 256, 256, 0, stream>>>(srcv, dstv, ea, deg, rowptr, fill,
                                                       csrc, cw, EE);

  const int PG = NN / 4;          // 12500 prop blocks (4 waves each)
  const int GB = (NN + 63) / 64;  // 782 gemm blocks

  // ---- Layer 1: 128 -> 64 ----
  gemm_kernel<128, 64, true,  false><<<GB, 256, 0, stream>>>(x,   W1 + 0 * 128 * 64, b1, h1, NN);
  prop_kernel<128, false><<<PG, 256, 0, stream>>>(rowptr, csrc, cw, x,   nullptr, TxA, NN, 1.f,  0.f);
  gemm_kernel<128, 64, false, false><<<GB, 256, 0, stream>>>(TxA, W1 + 1 * 128 * 64, b1, h1, NN);
  prop_kernel<128, true ><<<PG, 256, 0, stream>>>(rowptr, csrc, cw, TxA, x,   TxB, NN, 2.f, -1.f);
  gemm_kernel<128, 64, false, false><<<GB, 256, 0, stream>>>(TxB, W1 + 2 * 128 * 64, b1, h1, NN);
  prop_kernel<128, true ><<<PG, 256, 0, stream>>>(rowptr, csrc, cw, TxB, TxA, TxA, NN, 2.f, -1.f);
  gemm_kernel<128, 64, false, false><<<GB, 256, 0, stream>>>(TxA, W1 + 3 * 128 * 64, b1, h1, NN);
  prop_kernel<128, true ><<<PG, 256, 0, stream>>>(rowptr, csrc, cw, TxA, TxB, TxB, NN, 2.f, -1.f);
  gemm_kernel<128, 64, false, true ><<<GB, 256, 0, stream>>>(TxB, W1 + 4 * 128 * 64, b1, h1, NN);

  // ---- Layer 2: 64 -> 64 ----
  gemm_kernel<64, 64, true,  false><<<GB, 256, 0, stream>>>(h1,  W2 + 0 * 64 * 64, b2, h2, NN);
  prop_kernel<64, false><<<PG, 256, 0, stream>>>(rowptr, csrc, cw, h1,  nullptr, TxA, NN, 1.f,  0.f);
  gemm_kernel<64, 64, false, false><<<GB, 256, 0, stream>>>(TxA, W2 + 1 * 64 * 64, b2, h2, NN);
  prop_kernel<64, true ><<<PG, 256, 0, stream>>>(rowptr, csrc, cw, TxA, h1,  TxB, NN, 2.f, -1.f);
  gemm_kernel<64, 64, false, false><<<GB, 256, 0, stream>>>(TxB, W2 + 2 * 64 * 64, b2, h2, NN);
  prop_kernel<64, true ><<<PG, 256, 0, stream>>>(rowptr, csrc, cw, TxB, TxA, TxA, NN, 2.f, -1.f);
  gemm_kernel<64, 64, false, false><<<GB, 256, 0, stream>>>(TxA, W2 + 3 * 64 * 64, b2, h2, NN);
  prop_kernel<64, true ><<<PG, 256, 0, stream>>>(rowptr, csrc, cw, TxA, TxB, TxB, NN, 2.f, -1.f);
  gemm_kernel<64, 64, false, true ><<<GB, 256, 0, stream>>>(TxB, W2 + 4 * 64 * 64, b2, h2, NN);

  // ---- Layer 3: 64 -> 128 ----
  gemm_kernel<64, 128, true,  false><<<GB, 256, 0, stream>>>(h2,  W3 + 0 * 64 * 128, b3, h3, NN);
  prop_kernel<64, false><<<PG, 256, 0, stream>>>(rowptr, csrc, cw, h2,  nullptr, TxA, NN, 1.f,  0.f);
  gemm_kernel<64, 128, false, false><<<GB, 256, 0, stream>>>(TxA, W3 + 1 * 64 * 128, b3, h3, NN);
  prop_kernel<64, true ><<<PG, 256, 0, stream>>>(rowptr, csrc, cw, TxA, h2,  TxB, NN, 2.f, -1.f);
  gemm_kernel<64, 128, false, false><<<GB, 256, 0, stream>>>(TxB, W3 + 2 * 64 * 128, b3, h3, NN);
  prop_kernel<64, true ><<<PG, 256, 0, stream>>>(rowptr, csrc, cw, TxB, TxA, TxA, NN, 2.f, -1.f);
  gemm_kernel<64, 128, false, false><<<GB, 256, 0, stream>>>(TxA, W3 + 3 * 64 * 128, b3, h3, NN);
  prop_kernel<64, true ><<<PG, 256, 0, stream>>>(rowptr, csrc, cw, TxA, TxB, TxB, NN, 2.f, -1.f);
  gemm_kernel<64, 128, false, true ><<<GB, 256, 0, stream>>>(TxB, W3 + 4 * 64 * 128, b3, h3, NN);

  // ---- pool + head ----
  pool_feat<<<(NN * 128 + 255) / 256, 256, 0, stream>>>(h3, batch, pooled, NN);
  pool_cnt<<<(NN + 255) / 256, 256, 0, stream>>>(batch, gcnt, NN);
  head_kernel<<<GG, 128, 0, stream>>>(pooled, gcnt, Wl, bl, (float*)d_out);
}

// Round 2
// 1229.165 us; speedup vs baseline: 1.3914x; 1.3914x over previous
//
#include <hip/hip_runtime.h>
#include <hip/hip_bf16.h>

#define NN 50000
#define EE 1600000
#define GG 500

// ---------------- graph preprocessing ----------------

__global__ void deg_hist_kernel(const int* __restrict__ src, const int* __restrict__ dst,
                                const float* __restrict__ ea, float* __restrict__ deg,
                                int* __restrict__ cnt, int e) {
  int i = blockIdx.x * blockDim.x + threadIdx.x;
  if (i < e) {
    atomicAdd(&deg[src[i]], ea[i]);
    atomicAdd(&cnt[dst[i]], 1);
  }
}

__global__ void dinv_kernel(float* __restrict__ deg, int n) {
  int i = blockIdx.x * blockDim.x + threadIdx.x;
  if (i < n) { float d = deg[i]; deg[i] = (d > 0.f) ? (1.0f / sqrtf(d)) : 0.f; }
}

__global__ void scan1(const int* __restrict__ cnt, int* __restrict__ partial,
                      int* __restrict__ bsum, int n) {
  __shared__ int s[256];
  int t = threadIdx.x, i = blockIdx.x * 256 + t;
  int v = (i < n) ? cnt[i] : 0;
  s[t] = v; __syncthreads();
  for (int off = 1; off < 256; off <<= 1) {
    int xv = (t >= off) ? s[t - off] : 0;
    __syncthreads(); s[t] += xv; __syncthreads();
  }
  if (i < n) partial[i] = s[t];
  if (t == 255) bsum[blockIdx.x] = s[255];
}

__global__ void scan2(int* __restrict__ bsum, int nb) {
  __shared__ int s[256];
  int t = threadIdx.x;
  int v = (t < nb) ? bsum[t] : 0;
  s[t] = v; __syncthreads();
  for (int off = 1; off < 256; off <<= 1) {
    int xv = (t >= off) ? s[t - off] : 0;
    __syncthreads(); s[t] += xv; __syncthreads();
  }
  if (t < nb) bsum[t] = s[t];
}

__global__ void scan3(const int* __restrict__ partial, const int* __restrict__ bsum,
                      int* __restrict__ rowptr, int* __restrict__ cursor, int n) {
  int i = blockIdx.x * 256 + threadIdx.x;
  if (i < n) {
    int off = (blockIdx.x > 0) ? bsum[blockIdx.x - 1] : 0;
    rowptr[i + 1] = partial[i] + off;
    cursor[i] = (partial[i] + off) - 0;  // placeholder, fixed below
    if (i == 0) rowptr[0] = 0;
  }
}

__global__ void cursor_init(const int* __restrict__ rowptr, int* __restrict__ cursor, int n) {
  int i = blockIdx.x * 256 + threadIdx.x;
  if (i < n) cursor[i] = rowptr[i];
}

__global__ void scatter_kernel(const int* __restrict__ src, const int* __restrict__ dst,
                               const float* __restrict__ ea, const float* __restrict__ dinv,
                               int* __restrict__ cursor, uint2* __restrict__ edges, int e) {
  int i = blockIdx.x * blockDim.x + threadIdx.x;
  if (i < e) {
    int s = src[i], d = dst[i];
    float w = -dinv[s] * ea[i] * dinv[d];
    int pos = atomicAdd(&cursor[d], 1);
    edges[pos] = make_uint2((unsigned)s, __float_as_uint(w));
  }
}

// ---------------- sparse propagation (one wave per dst node, width 64) -------
// out = alpha * prop(g) + c1*a1 + c2*a2   [+ bias, relu]

template<int NADD, bool RELUB>
__global__ __launch_bounds__(256) void prop_kernel(
    const int* __restrict__ rowptr, const uint2* __restrict__ edges,
    const float* __restrict__ g, int sg,
    const float* __restrict__ a1, int sa1, float c1,
    const float* __restrict__ a2, int sa2, float c2,
    const float* __restrict__ bias,
    float* __restrict__ out, int so, int n, float alpha)
{
  int wv = blockIdx.x * 4 + (threadIdx.x >> 6);
  wv = __builtin_amdgcn_readfirstlane(wv);
  const int lane = threadIdx.x & 63;
  if (wv >= n) return;
  const int e0 = __builtin_amdgcn_readfirstlane(rowptr[wv]);
  const int e1 = __builtin_amdgcn_readfirstlane(rowptr[wv + 1]);
  float acc0 = 0.f, acc1 = 0.f;
  int j = e0;
  for (; j + 4 <= e1; j += 4) {
    uint2 p0 = edges[j + 0], p1 = edges[j + 1], p2 = edges[j + 2], p3 = edges[j + 3];
    int s0 = __builtin_amdgcn_readfirstlane((int)p0.x);
    int s1 = __builtin_amdgcn_readfirstlane((int)p1.x);
    int s2 = __builtin_amdgcn_readfirstlane((int)p2.x);
    int s3 = __builtin_amdgcn_readfirstlane((int)p3.x);
    float w0 = __uint_as_float((unsigned)__builtin_amdgcn_readfirstlane((int)p0.y));
    float w1 = __uint_as_float((unsigned)__builtin_amdgcn_readfirstlane((int)p1.y));
    float w2 = __uint_as_float((unsigned)__builtin_amdgcn_readfirstlane((int)p2.y));
    float w3 = __uint_as_float((unsigned)__builtin_amdgcn_readfirstlane((int)p3.y));
    float v0 = g[(size_t)s0 * sg + lane];
    float v1 = g[(size_t)s1 * sg + lane];
    float v2 = g[(size_t)s2 * sg + lane];
    float v3 = g[(size_t)s3 * sg + lane];
    acc0 += w0 * v0; acc1 += w1 * v1;
    acc0 += w2 * v2; acc1 += w3 * v3;
  }
  for (; j < e1; ++j) {
    uint2 p = edges[j];
    int s = __builtin_amdgcn_readfirstlane((int)p.x);
    float w = __uint_as_float((unsigned)__builtin_amdgcn_readfirstlane((int)p.y));
    acc0 += w * g[(size_t)s * sg + lane];
  }
  float r = alpha * (acc0 + acc1);
  if constexpr (NADD >= 1) r += c1 * a1[(size_t)wv * sa1 + lane];
  if constexpr (NADD >= 2) r += c2 * a2[(size_t)wv * sa2 + lane];
  if constexpr (RELUB) r = fmaxf(r + bias[lane], 0.f);
  out[(size_t)wv * so + lane] = r;
}

// ---------------- dense GEMM: C[n x Co] = A[n x Ci] @ W ----------------
// CAT: W is (K=5, Ci, 64) and output col j maps to W[j>>6][c][j&63]
// else: W is (Ci, Co) row-major.   BR: add bias + relu on store.

template<int Ci, int Co, bool CAT, bool BR>
__global__ __launch_bounds__(256) void gemm_kernel(const float* __restrict__ A,
    const float* __restrict__ W, const float* __restrict__ bias,
    float* __restrict__ C, int n)
{
  constexpr int TN = Co / 16;       // 20 or 8
  constexpr int KC = 32;
  constexpr int AST = KC + 4;       // 36: 16B-aligned rows, rotated banks
  __shared__ float Ws[KC * Co];
  __shared__ float As[64 * AST];
  const int tid = threadIdx.x;
  const int rb = blockIdx.x * 64;
  const int tx = tid & 15, ty = tid >> 4;
  float acc[4][TN] = {};

  for (int ko = 0; ko < Ci; ko += KC) {
    __syncthreads();
    // stage W chunk: KC x Co
    #pragma unroll
    for (int l = tid; l < KC * Co / 4; l += 256) {
      int c = l / (Co / 4);
      int j = (l % (Co / 4)) * 4;
      const float* srcp;
      if constexpr (CAT) {
        int k = j >> 6, f = j & 63;
        srcp = W + ((size_t)k * Ci + (ko + c)) * 64 + f;
      } else {
        srcp = W + (size_t)(ko + c) * Co + j;
      }
      *(float4*)&Ws[c * Co + j] = *(const float4*)srcp;
    }
    // stage A chunk: 64 x KC
    #pragma unroll
    for (int l = tid; l < 64 * KC / 4; l += 256) {
      int r = l / (KC / 4);
      int cq = (l % (KC / 4)) * 4;
      int row = rb + r;
      float4 v = make_float4(0.f, 0.f, 0.f, 0.f);
      if (row < n) v = *(const float4*)&A[(size_t)row * Ci + ko + cq];
      *(float4*)&As[r * AST + cq] = v;
    }
    __syncthreads();
    #pragma unroll
    for (int cc = 0; cc < KC; ++cc) {
      float b[TN];
      #pragma unroll
      for (int q = 0; q < TN; q += 4)
        *(float4*)&b[q] = *(const float4*)&Ws[cc * Co + tx * TN + q];
      float a0 = As[(ty * 4 + 0) * AST + cc];
      float a1 = As[(ty * 4 + 1) * AST + cc];
      float a2 = As[(ty * 4 + 2) * AST + cc];
      float a3 = As[(ty * 4 + 3) * AST + cc];
      #pragma unroll
      for (int q = 0; q < TN; q++) {
        acc[0][q] += a0 * b[q];
        acc[1][q] += a1 * b[q];
        acc[2][q] += a2 * b[q];
        acc[3][q] += a3 * b[q];
      }
    }
  }
  #pragma unroll
  for (int i = 0; i < 4; i++) {
    int row = rb + ty * 4 + i;
    if (row < n) {
      #pragma unroll
      for (int q = 0; q < TN; q += 4) {
        float4 v;
        v.x = acc[i][q + 0]; v.y = acc[i][q + 1];
        v.z = acc[i][q + 2]; v.w = acc[i][q + 3];
        if constexpr (BR) {
          v.x = fmaxf(v.x + bias[tx * TN + q + 0], 0.f);
          v.y = fmaxf(v.y + bias[tx * TN + q + 1], 0.f);
          v.z = fmaxf(v.z + bias[tx * TN + q + 2], 0.f);
          v.w = fmaxf(v.w + bias[tx * TN + q + 3], 0.f);
        }
        *(float4*)&C[(size_t)row * Co + tx * TN + q] = v;
      }
    }
  }
}

// ---------------- pooling + head ----------------

__global__ __launch_bounds__(128) void pool_kernel(const float* __restrict__ h,
    const int* __restrict__ batch, float* __restrict__ pooled, int n) {
  const int f = threadIdx.x;           // 0..127
  const int i0 = blockIdx.x * 64;
  const int iend = min(i0 + 64, n);
  int cur = batch[i0];
  float acc = 0.f;
  for (int i = i0; i < iend; ++i) {
    int b = batch[i];
    float v = h[(size_t)i * 128 + f];
    if (b != cur) {
      atomicAdd(&pooled[cur * 128 + f], acc);
      acc = 0.f; cur = b;
    }
    acc += v;
  }
  atomicAdd(&pooled[cur * 128 + f], acc);
}

__global__ void pool_cnt(const int* __restrict__ batch, float* __restrict__ gcnt, int n) {
  int i = blockIdx.x * blockDim.x + threadIdx.x;
  if (i < n) atomicAdd(&gcnt[batch[i]], 1.0f);
}

__global__ __launch_bounds__(128) void head_kernel(const float* __restrict__ pooled,
    const float* __restrict__ gcnt, const float* __restrict__ Wl,
    const float* __restrict__ bl, float* __restrict__ outp)
{
  int g = blockIdx.x, t = threadIdx.x;
  float denom = fmaxf(gcnt[g], 1.f);
  float p = pooled[g * 128 + t] / denom;
  __shared__ float s0[128], s1[128];
  s0[t] = p * Wl[t * 2 + 0];
  s1[t] = p * Wl[t * 2 + 1];
  __syncthreads();
  for (int off = 64; off > 0; off >>= 1) {
    if (t < off) { s0[t] += s0[t + off]; s1[t] += s1[t + off]; }
    __syncthreads();
  }
  if (t == 0) {
    float a = s0[0] + bl[0], b = s1[0] + bl[1];
    float m = fmaxf(a, b);
    float z = logf(expf(a - m) + expf(b - m)) + m;
    outp[g * 2 + 0] = a - z;
    outp[g * 2 + 1] = b - z;
  }
}

// ---------------- launch ----------------

extern "C" void kernel_launch(void* const* d_in, const int* in_sizes, int n_in,
                              void* d_out, int out_size, void* d_ws, size_t ws_size,
                              hipStream_t stream) {
  const float* x   = (const float*)d_in[0];
  const int*   ei  = (const int*)d_in[1];
  const float* ea  = (const float*)d_in[2];
  const int* batch = (const int*)d_in[3];
  const float* W1  = (const float*)d_in[4];
  const float* lb1 = (const float*)d_in[5];
  const float* W2  = (const float*)d_in[6];
  const float* lb2 = (const float*)d_in[7];
  const float* W3  = (const float*)d_in[8];
  const float* lb3 = (const float*)d_in[9];
  const float* Wl  = (const float*)d_in[10];
  const float* bl  = (const float*)d_in[11];
  const int* srcv = ei;
  const int* dstv = ei + EE;

  char* w = (char*)d_ws;
  auto alloc = [&](size_t bytes) -> char* {
    char* p = w; w += (bytes + 255) & ~(size_t)255; return p;
  };
  float* deg    = (float*)alloc((size_t)NN * 4);          // becomes dinv
  int*   rowptr = (int*)alloc((size_t)(NN + 1) * 4);
  int*   cnt    = (int*)alloc((size_t)NN * 4);            // becomes cursor
  int*   bsum   = (int*)alloc(256 * 4);
  uint2* edges  = (uint2*)alloc((size_t)EE * 8);
  float* Acat   = (float*)alloc((size_t)NN * 320 * 4);    // a_k / Clenshaw b_k / Tx_k
  float* Bcat   = (float*)alloc((size_t)NN * 320 * 4);    // layer2 blocks; later h3
  float* h1     = (float*)alloc((size_t)NN * 64 * 4);
  float* pooled = (float*)alloc((size_t)(GG * 128 + GG) * 4);
  float* gcnt   = pooled + GG * 128;
  int*   partial = (int*)Acat;     // scan scratch (Acat unused until GEMM1)
  float* h3 = Bcat;                // layer-3 output reuses Bcat

  hipMemsetAsync(deg, 0, (size_t)NN * 4, stream);
  hipMemsetAsync(cnt, 0, (size_t)NN * 4, stream);
  hipMemsetAsync(pooled, 0, (size_t)(GG * 128 + GG) * 4, stream);

  deg_hist_kernel<<<(EE + 255) / 256, 256, 0, stream>>>(srcv, dstv, ea, deg, cnt, EE);
  dinv_kernel<<<(NN + 255) / 256, 256, 0, stream>>>(deg, NN);
  const int nb = (NN + 255) / 256;  // 196
  scan1<<<nb, 256, 0, stream>>>(cnt, partial, bsum, NN);
  scan2<<<1, 256, 0, stream>>>(bsum, nb);
  scan3<<<nb, 256, 0, stream>>>(partial, bsum, rowptr, cnt, NN);
  cursor_init<<<nb, 256, 0, stream>>>(rowptr, cnt, NN);
  scatter_kernel<<<(EE + 255) / 256, 256, 0, stream>>>(srcv, dstv, ea, deg, cnt, edges, EE);

  const int PG = (NN + 3) / 4;      // 12500 prop blocks (4 waves each)
  const int GB = (NN + 63) / 64;    // 782 gemm blocks

  float* A0 = Acat + 0 * 64;  float* A1 = Acat + 1 * 64;  float* A2 = Acat + 2 * 64;
  float* A3 = Acat + 3 * 64;  float* A4 = Acat + 4 * 64;
  float* B0 = Bcat + 0 * 64;  float* B1 = Bcat + 1 * 64;  float* B2 = Bcat + 2 * 64;
  float* B3 = Bcat + 3 * 64;  float* B4 = Bcat + 4 * 64;
  const int S = 320;

  // ---- Layer 1 (Clenshaw): a_k = x @ W1_k  (one 128->320 GEMM) ----
  gemm_kernel<128, 320, true, false><<<GB, 256, 0, stream>>>(x, W1, nullptr, Acat, NN);
  // b3 = a3 + 2 P b4
  prop_kernel<1, false><<<PG, 256, 0, stream>>>(rowptr, edges, A4, S, A3, S, 1.f,
      nullptr, 0, 0.f, nullptr, A3, S, NN, 2.f);
  // b2 = a2 + 2 P b3 - b4
  prop_kernel<2, false><<<PG, 256, 0, stream>>>(rowptr, edges, A3, S, A2, S, 1.f,
      A4, S, -1.f, nullptr, A2, S, NN, 2.f);
  // b1 = a1 + 2 P b2 - b3
  prop_kernel<2, false><<<PG, 256, 0, stream>>>(rowptr, edges, A2, S, A1, S, 1.f,
      A3, S, -1.f, nullptr, A1, S, NN, 2.f);
  // h1 = relu(a0 + P b1 - b2 + bias)
  prop_kernel<2, true><<<PG, 256, 0, stream>>>(rowptr, edges, A1, S, A0, S, 1.f,
      A2, S, -1.f, lb1, h1, 64, NN, 1.f);

  // ---- Layer 2 (Clenshaw): a_k = h1 @ W2_k ----
  gemm_kernel<64, 320, true, false><<<GB, 256, 0, stream>>>(h1, W2, nullptr, Bcat, NN);
  prop_kernel<1, false><<<PG, 256, 0, stream>>>(rowptr, edges, B4, S, B3, S, 1.f,
      nullptr, 0, 0.f, nullptr, B3, S, NN, 2.f);
  prop_kernel<2, false><<<PG, 256, 0, stream>>>(rowptr, edges, B3, S, B2, S, 1.f,
      B4, S, -1.f, nullptr, B2, S, NN, 2.f);
  prop_kernel<2, false><<<PG, 256, 0, stream>>>(rowptr, edges, B2, S, B1, S, 1.f,
      B3, S, -1.f, nullptr, B1, S, NN, 2.f);
  // h2 = relu(a0 + P b1 - b2 + bias) -> written strided into Acat block 0 (Tx0)
  prop_kernel<2, true><<<PG, 256, 0, stream>>>(rowptr, edges, B1, S, B0, S, 1.f,
      B2, S, -1.f, lb2, A0, S, NN, 1.f);

  // ---- Layer 3 (forward recursion, Tx_k in Acat blocks) ----
  // Tx1 = P Tx0
  prop_kernel<0, false><<<PG, 256, 0, stream>>>(rowptr, edges, A0, S, nullptr, 0, 0.f,
      nullptr, 0, 0.f, nullptr, A1, S, NN, 1.f);
  // Tx2 = 2 P Tx1 - Tx0
  prop_kernel<1, false><<<PG, 256, 0, stream>>>(rowptr, edges, A1, S, A0, S, -1.f,
      nullptr, 0, 0.f, nullptr, A2, S, NN, 2.f);
  prop_kernel<1, false><<<PG, 256, 0, stream>>>(rowptr, edges, A2, S, A1, S, -1.f,
      nullptr, 0, 0.f, nullptr, A3, S, NN, 2.f);
  prop_kernel<1, false><<<PG, 256, 0, stream>>>(rowptr, edges, A3, S, A2, S, -1.f,
      nullptr, 0, 0.f, nullptr, A4, S, NN, 2.f);
  // h3 = relu([Tx0|..|Tx4] @ W3stack + b3)   (W3 natural layout is (320,128))
  gemm_kernel<320, 128, false, true><<<GB, 256, 0, stream>>>(Acat, W3, lb3, h3, NN);

  // ---- pool + head ----
  pool_kernel<<<(NN + 63) / 64, 128, 0, stream>>>(h3, batch, pooled, NN);
  pool_cnt<<<(NN + 255) / 256, 256, 0, stream>>>(batch, gcnt, NN);
  head_kernel<<<GG, 128, 0, stream>>>(pooled, gcnt, Wl, bl, (float*)d_out);
}

// Round 3
// 884.132 us; speedup vs baseline: 1.9344x; 1.3903x over previous
//
#include <hip/hip_runtime.h>
#include <hip/hip_bf16.h>

#define NN 50000
#define EE 1600000
#define GG 500

typedef __bf16 bf16x8 __attribute__((ext_vector_type(8)));
typedef float  f32x4  __attribute__((ext_vector_type(4)));

__device__ __forceinline__ float b2f(ushort u) {
  return __uint_as_float(((unsigned)u) << 16);
}
__device__ __forceinline__ ushort f2b(float f) {
  unsigned u = __float_as_uint(f);
  unsigned r = (u + 0x7fff + ((u >> 16) & 1)) >> 16;   // RNE
  return (ushort)r;
}

// ---------------- graph preprocessing ----------------

__global__ void deg_hist_kernel(const int* __restrict__ src, const int* __restrict__ dst,
                                const float* __restrict__ ea, float* __restrict__ deg,
                                int* __restrict__ cnt, int e) {
  int i = blockIdx.x * blockDim.x + threadIdx.x;
  if (i < e) {
    atomicAdd(&deg[src[i]], ea[i]);
    atomicAdd(&cnt[dst[i]], 1);
  }
}

__global__ void dinv_kernel(float* __restrict__ deg, int n) {
  int i = blockIdx.x * blockDim.x + threadIdx.x;
  if (i < n) { float d = deg[i]; deg[i] = (d > 0.f) ? (1.0f / sqrtf(d)) : 0.f; }
}

__global__ void scan1(const int* __restrict__ cnt, int* __restrict__ partial,
                      int* __restrict__ bsum, int n) {
  __shared__ int s[256];
  int t = threadIdx.x, i = blockIdx.x * 256 + t;
  int v = (i < n) ? cnt[i] : 0;
  s[t] = v; __syncthreads();
  for (int off = 1; off < 256; off <<= 1) {
    int xv = (t >= off) ? s[t - off] : 0;
    __syncthreads(); s[t] += xv; __syncthreads();
  }
  if (i < n) partial[i] = s[t];
  if (t == 255) bsum[blockIdx.x] = s[255];
}

__global__ void scan2(int* __restrict__ bsum, int nb) {
  __shared__ int s[256];
  int t = threadIdx.x;
  int v = (t < nb) ? bsum[t] : 0;
  s[t] = v; __syncthreads();
  for (int off = 1; off < 256; off <<= 1) {
    int xv = (t >= off) ? s[t - off] : 0;
    __syncthreads(); s[t] += xv; __syncthreads();
  }
  if (t < nb) bsum[t] = s[t];
}

__global__ void scan3(const int* __restrict__ partial, const int* __restrict__ bsum,
                      int* __restrict__ rowptr, int n) {
  int i = blockIdx.x * 256 + threadIdx.x;
  if (i < n) {
    int off = (blockIdx.x > 0) ? bsum[blockIdx.x - 1] : 0;
    rowptr[i + 1] = partial[i] + off;
    if (i == 0) rowptr[0] = 0;
  }
}

__global__ void cursor_init(const int* __restrict__ rowptr, int* __restrict__ cursor, int n) {
  int i = blockIdx.x * 256 + threadIdx.x;
  if (i < n) cursor[i] = rowptr[i];
}

__global__ void scatter_kernel(const int* __restrict__ src, const int* __restrict__ dst,
                               const float* __restrict__ ea, const float* __restrict__ dinv,
                               int* __restrict__ cursor, uint2* __restrict__ edges, int e) {
  int i = blockIdx.x * blockDim.x + threadIdx.x;
  if (i < e) {
    int s = src[i], d = dst[i];
    float w = -dinv[s] * ea[i] * dinv[d];
    int pos = atomicAdd(&cursor[d], 1);
    edges[pos] = make_uint2((unsigned)s, __float_as_uint(w));
  }
}

// ---------------- dtype conversions ----------------

__global__ void cvt_x(const float* __restrict__ x, ushort* __restrict__ xb, int n4) {
  int i = blockIdx.x * 256 + threadIdx.x;
  if (i < n4) {
    float4 v = ((const float4*)x)[i];
    ushort4 o;
    o.x = f2b(v.x); o.y = f2b(v.y); o.z = f2b(v.z); o.w = f2b(v.w);
    ((ushort4*)xb)[i] = o;
  }
}

// Wt1[320][128] = W1[j>>6][k][j&63]; Wt2[320][64]; Wt3[128][320] = W3stack^T
__global__ void cvt_w(const float* __restrict__ W1, const float* __restrict__ W2,
                      const float* __restrict__ W3, ushort* __restrict__ Wt1,
                      ushort* __restrict__ Wt2, ushort* __restrict__ Wt3) {
  int i = blockIdx.x * 256 + threadIdx.x;
  if (i < 320 * 128) {
    int j = i / 128, k = i % 128;
    Wt1[i] = f2b(W1[((size_t)(j >> 6) * 128 + k) * 64 + (j & 63)]);
  } else if (i < 320 * 128 + 320 * 64) {
    int t = i - 320 * 128; int j = t / 64, k = t % 64;
    Wt2[t] = f2b(W2[((size_t)(j >> 6) * 64 + k) * 64 + (j & 63)]);
  } else if (i < 320 * 128 + 320 * 64 + 128 * 320) {
    int t = i - 320 * 128 - 320 * 64; int j = t / 320, k = t % 320;
    Wt3[t] = f2b(W3[(size_t)k * 128 + j]);
  }
}

// ---------------- sparse propagation (one wave per dst node, width 64, bf16) --
// out = alpha * prop(g) + c1*a1 + c2*a2   [+ bias, relu]

template<int NADD, bool RELUB>
__global__ __launch_bounds__(256) void prop_kernel(
    const int* __restrict__ rowptr, const uint2* __restrict__ edges,
    const ushort* __restrict__ g, int sg,
    const ushort* __restrict__ a1, int sa1, float c1,
    const ushort* __restrict__ a2, int sa2, float c2,
    const float* __restrict__ bias,
    ushort* __restrict__ out, int so, int n, float alpha)
{
  int wv = blockIdx.x * 4 + (threadIdx.x >> 6);
  wv = __builtin_amdgcn_readfirstlane(wv);
  const int lane = threadIdx.x & 63;
  if (wv >= n) return;
  const int e0 = __builtin_amdgcn_readfirstlane(rowptr[wv]);
  const int e1 = __builtin_amdgcn_readfirstlane(rowptr[wv + 1]);
  float acc0 = 0.f, acc1 = 0.f;
  int j = e0;
  for (; j + 4 <= e1; j += 4) {
    uint2 p0 = edges[j + 0], p1 = edges[j + 1], p2 = edges[j + 2], p3 = edges[j + 3];
    int s0 = __builtin_amdgcn_readfirstlane((int)p0.x);
    int s1 = __builtin_amdgcn_readfirstlane((int)p1.x);
    int s2 = __builtin_amdgcn_readfirstlane((int)p2.x);
    int s3 = __builtin_amdgcn_readfirstlane((int)p3.x);
    float w0 = __uint_as_float((unsigned)__builtin_amdgcn_readfirstlane((int)p0.y));
    float w1 = __uint_as_float((unsigned)__builtin_amdgcn_readfirstlane((int)p1.y));
    float w2 = __uint_as_float((unsigned)__builtin_amdgcn_readfirstlane((int)p2.y));
    float w3 = __uint_as_float((unsigned)__builtin_amdgcn_readfirstlane((int)p3.y));
    float v0 = b2f(g[(size_t)s0 * sg + lane]);
    float v1 = b2f(g[(size_t)s1 * sg + lane]);
    float v2 = b2f(g[(size_t)s2 * sg + lane]);
    float v3 = b2f(g[(size_t)s3 * sg + lane]);
    acc0 += w0 * v0; acc1 += w1 * v1;
    acc0 += w2 * v2; acc1 += w3 * v3;
  }
  for (; j < e1; ++j) {
    uint2 p = edges[j];
    int s = __builtin_amdgcn_readfirstlane((int)p.x);
    float w = __uint_as_float((unsigned)__builtin_amdgcn_readfirstlane((int)p.y));
    acc0 += w * b2f(g[(size_t)s * sg + lane]);
  }
  float r = alpha * (acc0 + acc1);
  if constexpr (NADD >= 1) r += c1 * b2f(a1[(size_t)wv * sa1 + lane]);
  if constexpr (NADD >= 2) r += c2 * b2f(a2[(size_t)wv * sa2 + lane]);
  if constexpr (RELUB) r = fmaxf(r + bias[lane], 0.f);
  out[(size_t)wv * so + lane] = f2b(r);
}

// ---------------- MFMA GEMM: C[n x Co](bf16) = A[n x Ci](bf16) @ Wt^T --------
// Wt is [Co][Ci] bf16 (i.e. B^T row-major). No LDS: B-frags from L1/L2,
// A-frags from global. Block = 4 waves; wave = 4 strips of 16 rows x 64 cols.
// grid = (ceil(n/256), Co/64).

template<int Ci, int Co, bool BR>
__global__ __launch_bounds__(256) void gemm_mfma(const ushort* __restrict__ A,
    const ushort* __restrict__ Wt, const float* __restrict__ bias,
    ushort* __restrict__ C, int n)
{
  const int lane = threadIdx.x & 63;
  const int wid  = threadIdx.x >> 6;
  const int rb = blockIdx.x * 256;
  const int cb = blockIdx.y * 64;
  const int lr = lane & 15;            // row/col within fragment
  const int lk = (lane >> 4) << 3;     // k offset: 0,8,16,24
  f32x4 acc[4][4] = {};

  for (int kc = 0; kc < Ci; kc += 64) {
    bf16x8 bfrag[2][4];
    #pragma unroll
    for (int ks = 0; ks < 2; ++ks)
      #pragma unroll
      for (int nt = 0; nt < 4; ++nt)
        bfrag[ks][nt] = *(const bf16x8*)&Wt[(size_t)(cb + nt * 16 + lr) * Ci + kc + ks * 32 + lk];
    #pragma unroll
    for (int s = 0; s < 4; ++s) {
      const int row = rb + (wid * 4 + s) * 16 + lr;
      const ushort* ap = &A[(size_t)row * Ci + kc + lk];
      #pragma unroll
      for (int ks = 0; ks < 2; ++ks) {
        bf16x8 af = {};
        if (row < n) af = *(const bf16x8*)(ap + ks * 32);
        #pragma unroll
        for (int nt = 0; nt < 4; ++nt)
          acc[s][nt] = __builtin_amdgcn_mfma_f32_16x16x32_bf16(af, bfrag[ks][nt], acc[s][nt], 0, 0, 0);
      }
    }
  }

  #pragma unroll
  for (int s = 0; s < 4; ++s) {
    #pragma unroll
    for (int nt = 0; nt < 4; ++nt) {
      const int col = cb + nt * 16 + lr;
      #pragma unroll
      for (int r = 0; r < 4; ++r) {
        const int row = rb + (wid * 4 + s) * 16 + ((lane >> 4) << 2) + r;
        if (row < n) {
          float v = acc[s][nt][r];
          if constexpr (BR) v = fmaxf(v + bias[col], 0.f);
          C[(size_t)row * Co + col] = f2b(v);
        }
      }
    }
  }
}

// ---------------- pooling + head ----------------

__global__ __launch_bounds__(128) void pool_kernel(const ushort* __restrict__ h,
    const int* __restrict__ batch, float* __restrict__ pooled, int n) {
  const int f = threadIdx.x;           // 0..127
  const int i0 = blockIdx.x * 64;
  const int iend = min(i0 + 64, n);
  int cur = batch[i0];
  float acc = 0.f;
  for (int i = i0; i < iend; ++i) {
    int b = batch[i];
    float v = b2f(h[(size_t)i * 128 + f]);
    if (b != cur) {
      atomicAdd(&pooled[cur * 128 + f], acc);
      acc = 0.f; cur = b;
    }
    acc += v;
  }
  atomicAdd(&pooled[cur * 128 + f], acc);
}

__global__ void pool_cnt(const int* __restrict__ batch, float* __restrict__ gcnt, int n) {
  int i = blockIdx.x * blockDim.x + threadIdx.x;
  if (i < n) atomicAdd(&gcnt[batch[i]], 1.0f);
}

__global__ __launch_bounds__(128) void head_kernel(const float* __restrict__ pooled,
    const float* __restrict__ gcnt, const float* __restrict__ Wl,
    const float* __restrict__ bl, float* __restrict__ outp)
{
  int g = blockIdx.x, t = threadIdx.x;
  float denom = fmaxf(gcnt[g], 1.f);
  float p = pooled[g * 128 + t] / denom;
  __shared__ float s0[128], s1[128];
  s0[t] = p * Wl[t * 2 + 0];
  s1[t] = p * Wl[t * 2 + 1];
  __syncthreads();
  for (int off = 64; off > 0; off >>= 1) {
    if (t < off) { s0[t] += s0[t + off]; s1[t] += s1[t + off]; }
    __syncthreads();
  }
  if (t == 0) {
    float a = s0[0] + bl[0], b = s1[0] + bl[1];
    float m = fmaxf(a, b);
    float z = logf(expf(a - m) + expf(b - m)) + m;
    outp[g * 2 + 0] = a - z;
    outp[g * 2 + 1] = b - z;
  }
}

// ---------------- launch ----------------

extern "C" void kernel_launch(void* const* d_in, const int* in_sizes, int n_in,
                              void* d_out, int out_size, void* d_ws, size_t ws_size,
                              hipStream_t stream) {
  const float* x   = (const float*)d_in[0];
  const int*   ei  = (const int*)d_in[1];
  const float* ea  = (const float*)d_in[2];
  const int* batch = (const int*)d_in[3];
  const float* W1  = (const float*)d_in[4];
  const float* lb1 = (const float*)d_in[5];
  const float* W2  = (const float*)d_in[6];
  const float* lb2 = (const float*)d_in[7];
  const float* W3  = (const float*)d_in[8];
  const float* lb3 = (const float*)d_in[9];
  const float* Wl  = (const float*)d_in[10];
  const float* bl  = (const float*)d_in[11];
  const int* srcv = ei;
  const int* dstv = ei + EE;

  char* w = (char*)d_ws;
  auto alloc = [&](size_t bytes) -> char* {
    char* p = w; w += (bytes + 255) & ~(size_t)255; return p;
  };
  float* deg    = (float*)alloc((size_t)NN * 4);          // becomes dinv
  int*   rowptr = (int*)alloc((size_t)(NN + 1) * 4);
  int*   cnt    = (int*)alloc((size_t)NN * 4);            // becomes cursor
  int*   bsum   = (int*)alloc(256 * 4);
  uint2* edges  = (uint2*)alloc((size_t)EE * 8);
  ushort* xb    = (ushort*)alloc((size_t)NN * 128 * 2);
  ushort* Acat  = (ushort*)alloc((size_t)NN * 320 * 2);   // a_k / Clenshaw / Tx_k
  ushort* Bcat  = (ushort*)alloc((size_t)NN * 320 * 2);   // layer2 blocks; later h3
  ushort* h1    = (ushort*)alloc((size_t)NN * 64 * 2);
  ushort* Wt1   = (ushort*)alloc((size_t)320 * 128 * 2);
  ushort* Wt2   = (ushort*)alloc((size_t)320 * 64 * 2);
  ushort* Wt3   = (ushort*)alloc((size_t)128 * 320 * 2);
  float* pooled = (float*)alloc((size_t)(GG * 128 + GG) * 4);
  float* gcnt   = pooled + GG * 128;
  int*   partial = (int*)Acat;     // scan scratch (Acat unused until GEMM1)
  ushort* h3 = Bcat;               // layer-3 output reuses Bcat

  hipMemsetAsync(deg, 0, (size_t)NN * 4, stream);
  hipMemsetAsync(cnt, 0, (size_t)NN * 4, stream);
  hipMemsetAsync(pooled, 0, (size_t)(GG * 128 + GG) * 4, stream);

  deg_hist_kernel<<<(EE + 255) / 256, 256, 0, stream>>>(srcv, dstv, ea, deg, cnt, EE);
  dinv_kernel<<<(NN + 255) / 256, 256, 0, stream>>>(deg, NN);
  const int nb = (NN + 255) / 256;  // 196
  scan1<<<nb, 256, 0, stream>>>(cnt, partial, bsum, NN);
  scan2<<<1, 256, 0, stream>>>(bsum, nb);
  scan3<<<nb, 256, 0, stream>>>(partial, bsum, rowptr, NN);
  cursor_init<<<nb, 256, 0, stream>>>(rowptr, cnt, NN);
  scatter_kernel<<<(EE + 255) / 256, 256, 0, stream>>>(srcv, dstv, ea, deg, cnt, edges, EE);

  cvt_x<<<(NN * 128 / 4 + 255) / 256, 256, 0, stream>>>(x, xb, NN * 128 / 4);
  cvt_w<<<(320 * 128 + 320 * 64 + 128 * 320 + 255) / 256, 256, 0, stream>>>(
      W1, W2, W3, Wt1, Wt2, Wt3);

  const int PG = (NN + 3) / 4;       // prop blocks (4 waves each)
  const int GX = (NN + 255) / 256;   // gemm row-blocks

  ushort* A0 = Acat + 0 * 64;  ushort* A1 = Acat + 1 * 64;  ushort* A2 = Acat + 2 * 64;
  ushort* A3 = Acat + 3 * 64;  ushort* A4 = Acat + 4 * 64;
  ushort* B0 = Bcat + 0 * 64;  ushort* B1 = Bcat + 1 * 64;  ushort* B2 = Bcat + 2 * 64;
  ushort* B3 = Bcat + 3 * 64;  ushort* B4 = Bcat + 4 * 64;
  const int S = 320;

  // ---- Layer 1 (Clenshaw): a_k = x @ W1_k  -> Acat[50000][320] ----
  gemm_mfma<128, 320, false><<<dim3(GX, 5), 256, 0, stream>>>(xb, Wt1, nullptr, Acat, NN);
  prop_kernel<1, false><<<PG, 256, 0, stream>>>(rowptr, edges, A4, S, A3, S, 1.f,
      nullptr, 0, 0.f, nullptr, A3, S, NN, 2.f);
  prop_kernel<2, false><<<PG, 256, 0, stream>>>(rowptr, edges, A3, S, A2, S, 1.f,
      A4, S, -1.f, nullptr, A2, S, NN, 2.f);
  prop_kernel<2, false><<<PG, 256, 0, stream>>>(rowptr, edges, A2, S, A1, S, 1.f,
      A3, S, -1.f, nullptr, A1, S, NN, 2.f);
  prop_kernel<2, true><<<PG, 256, 0, stream>>>(rowptr, edges, A1, S, A0, S, 1.f,
      A2, S, -1.f, lb1, h1, 64, NN, 1.f);

  // ---- Layer 2 (Clenshaw): a_k = h1 @ W2_k -> Bcat ----
  gemm_mfma<64, 320, false><<<dim3(GX, 5), 256, 0, stream>>>(h1, Wt2, nullptr, Bcat, NN);
  prop_kernel<1, false><<<PG, 256, 0, stream>>>(rowptr, edges, B4, S, B3, S, 1.f,
      nullptr, 0, 0.f, nullptr, B3, S, NN, 2.f);
  prop_kernel<2, false><<<PG, 256, 0, stream>>>(rowptr, edges, B3, S, B2, S, 1.f,
      B4, S, -1.f, nullptr, B2, S, NN, 2.f);
  prop_kernel<2, false><<<PG, 256, 0, stream>>>(rowptr, edges, B2, S, B1, S, 1.f,
      B3, S, -1.f, nullptr, B1, S, NN, 2.f);
  // h2 -> Acat block 0 (Tx0), strided
  prop_kernel<2, true><<<PG, 256, 0, stream>>>(rowptr, edges, B1, S, B0, S, 1.f,
      B2, S, -1.f, lb2, A0, S, NN, 1.f);

  // ---- Layer 3 (forward recursion, Tx_k in Acat blocks) ----
  prop_kernel<0, false><<<PG, 256, 0, stream>>>(rowptr, edges, A0, S, nullptr, 0, 0.f,
      nullptr, 0, 0.f, nullptr, A1, S, NN, 1.f);
  prop_kernel<1, false><<<PG, 256, 0, stream>>>(rowptr, edges, A1, S, A0, S, -1.f,
      nullptr, 0, 0.f, nullptr, A2, S, NN, 2.f);
  prop_kernel<1, false><<<PG, 256, 0, stream>>>(rowptr, edges, A2, S, A1, S, -1.f,
      nullptr, 0, 0.f, nullptr, A3, S, NN, 2.f);
  prop_kernel<1, false><<<PG, 256, 0, stream>>>(rowptr, edges, A3, S, A2, S, -1.f,
      nullptr, 0, 0.f, nullptr, A4, S, NN, 2.f);
  // h3 = relu([Tx0|..|Tx4] @ W3stack + b3)
  gemm_mfma<320, 128, true><<<dim3(GX, 2), 256, 0, stream>>>(Acat, Wt3, lb3, h3, NN);

  // ---- pool + head ----
  pool_kernel<<<(NN + 63) / 64, 128, 0, stream>>>(h3, batch, pooled, NN);
  pool_cnt<<<(NN + 255) / 256, 256, 0, stream>>>(batch, gcnt, NN);
  head_kernel<<<GG, 128, 0, stream>>>(pooled, gcnt, Wl, bl, (float*)d_out);
}